// Round 6
// baseline (465.644 us; speedup 1.0000x reference)
//
#include <hip/hip_runtime.h>
#include <hip/hip_bf16.h>

typedef __attribute__((ext_vector_type(8))) short short8;
typedef __attribute__((ext_vector_type(4))) short short4v;
typedef __attribute__((ext_vector_type(4))) float f32x4;
typedef __attribute__((ext_vector_type(16))) float f32x16;

#define MFMA32(a,b,c) __builtin_amdgcn_mfma_f32_32x32x16_bf16(a,b,c,0,0,0)

static __device__ __forceinline__ short f2bf(float f){
    union{float f;unsigned u;}x; x.f=f;
    unsigned r=(x.u+0x7FFFu+((x.u>>16)&1u))>>16;
    return (short)r;
}

static __device__ __forceinline__ unsigned pkbf(float lo, float hi){
    unsigned r;
    asm("v_cvt_pk_bf16_f32 %0, %1, %2" : "=v"(r) : "v"(lo), "v"(hi));
    return r;
}

static __device__ __forceinline__ void gl_lds16(const void* g, void* l){
    __builtin_amdgcn_global_load_lds(
        (const __attribute__((address_space(1))) unsigned int*)g,
        (__attribute__((address_space(3))) unsigned int*)l, 16, 0, 0);
}

// build PV B-fragment: lane (ln,hi) needs P[q=ln][kv = chunk + hi*8 + e], e=0..7.
// own regs hold kv (r&3)+8*(r>>2)+4*hi; partner (lane^32) holds the other half.
static __device__ __forceinline__ short8 pfrag(int hi,
        float e0,float e1,float e2,float e3,
        float e4,float e5,float e6,float e7){
    unsigned a01 = pkbf(e0,e1), a23 = pkbf(e2,e3);
    unsigned a45 = pkbf(e4,e5), a67 = pkbf(e6,e7);
    unsigned b01 = __shfl_xor(a01, 32);
    unsigned b23 = __shfl_xor(a23, 32);
    unsigned b45 = __shfl_xor(a45, 32);
    unsigned b67 = __shfl_xor(a67, 32);
    union{ unsigned u[4]; short8 s; } w;
    w.u[0] = hi ? b45 : a01;
    w.u[1] = hi ? b67 : a23;
    w.u[2] = hi ? a45 : b01;
    w.u[3] = hi ? a67 : b23;
    return w.s;
}

// B=2, S=2048, H=32, HK=8, D=128, G=4
constexpr int S_=2048, H_=32, HK_=8, D_=128;
constexpr int KVBLK=64;

// ---- fused prepass: K repack -> bf16 [B,HK,S,D]; V transpose -> bf16 [B,HK,D,S] ----
__global__ __launch_bounds__(256) void prep(const float* __restrict__ k, const float* __restrict__ v,
                                            short* __restrict__ kb, short* __restrict__ vt){
    __shared__ short tile[64*65];
    int bid = blockIdx.x;
    if (bid < 4096){
        int t = bid*256 + threadIdx.x;
        int e = t*4;
        int d  = e & 127;
        int hk = (e>>7) & 7;
        int s  = (e>>10) & 2047;
        int b  = e>>21;
        f32x4 x = *(const f32x4*)(k + ((size_t)((b*S_+s)*HK_+hk))*D_ + d);
        short4v o;
        o[0]=f2bf(x[0]); o[1]=f2bf(x[1]); o[2]=f2bf(x[2]); o[3]=f2bf(x[3]);
        *(short4v*)(kb + ((size_t)((b*HK_+hk)*S_+s))*D_ + d) = o;
    } else {
        bid -= 4096;
        int d0 = (bid & 1)*64;
        int s0 = ((bid>>1) & 31)*64;
        int hk = (bid>>6) & 7;
        int b  = bid>>9;
        int tid = threadIdx.x;
        #pragma unroll
        for(int i=0;i<4;i++){
            int idx = i*1024 + tid*4;
            int r = idx>>6, c = idx&63;
            f32x4 x = *(const f32x4*)(v + ((size_t)((b*S_+s0+r)*HK_+hk))*D_ + d0 + c);
            tile[(c+0)*65 + r] = f2bf(x[0]);
            tile[(c+1)*65 + r] = f2bf(x[1]);
            tile[(c+2)*65 + r] = f2bf(x[2]);
            tile[(c+3)*65 + r] = f2bf(x[3]);
        }
        __syncthreads();
        #pragma unroll
        for(int i=0;i<4;i++){
            int idx = i*1024 + tid*4;
            int dr = idx>>6, c = idx&63;
            short4v o;
            o[0]=tile[dr*65+c]; o[1]=tile[dr*65+c+1]; o[2]=tile[dr*65+c+2]; o[3]=tile[dr*65+c+3];
            *(short4v*)(vt + ((size_t)((b*HK_+hk)*D_ + d0+dr))*S_ + s0 + c) = o;
        }
    }
}

// ---- main attention: 4 waves x 32 q-rows, single-buffered KV, 4 blocks/CU ----
__global__ __launch_bounds__(256,4) void attn_fwd(
    const float* __restrict__ q, const short* __restrict__ kb,
    const short* __restrict__ vtb, float* __restrict__ out)
{
    // K tile [64][128]bf16 (rows 256B), V^T tile [128][64]bf16 (rows 128B),
    // single-buffered, XOR-swizzled (^((row&7)<<4))  -> 32 KB total
    __shared__ __align__(16) unsigned char kls[KVBLK*D_*2];   // 16KB
    __shared__ __align__(16) unsigned char vls[D_*KVBLK*2];   // 16KB

    const int bid  = blockIdx.x;                 // 1024 blocks
    // XCD-aware heavy-first: xcd = bid&7 keeps 2 (b,hk) KV groups in each L2;
    // c decreases as dispatch index grows -> heavy chunks start first.
    const int xcd  = bid & 7;
    const int r_   = bid >> 3;                   // 0..127
    const int c    = 15 - (r_ >> 3);             // q-chunk 15..0
    const int sub  = r_ & 7;
    const int kvg  = xcd*2 + (sub >> 2);         // 0..15 = b*8+hk
    const int b    = kvg >> 3;
    const int hk   = kvg & 7;
    const int h    = hk*4 + (sub & 3);
    const int q0   = c * 128;

    const int tid  = threadIdx.x;
    const int wave = tid >> 6;                   // 0..3
    const int ln   = tid & 31;
    const int hi   = (tid >> 5) & 1;
    const int qg   = q0 + wave*32 + ln;          // this lane's q row/column

    const float qscale = 0.08838834764831845f * 1.4426950408889634f; // /sqrt(D)*log2e

    const short* kt_base = kb  + (size_t)(b*HK_+hk)*S_*D_;
    const short* vt_base = vtb + (size_t)(b*HK_+hk)*D_*S_;

    // ---- Q fragments: lane holds Q[qg][16kk+8hi .. +7], scaled ----
    short8 qf[8];
    {
        const float* qp = q + ((size_t)(b*S_ + qg)*H_ + h)*D_;
        #pragma unroll
        for(int kk=0;kk<8;kk++){
            int d0 = kk*16 + hi*8;
            f32x4 a = *(const f32x4*)(qp + d0);
            f32x4 cc= *(const f32x4*)(qp + d0 + 4);
            union{ unsigned u[4]; short8 s; } w;
            w.u[0]=pkbf(a[0]*qscale, a[1]*qscale);
            w.u[1]=pkbf(a[2]*qscale, a[3]*qscale);
            w.u[2]=pkbf(cc[0]*qscale, cc[1]*qscale);
            w.u[3]=pkbf(cc[2]*qscale, cc[3]*qscale);
            qf[kk]=w.s;
        }
    }

    f32x16 oac[4];
    #pragma unroll
    for(int dt=0;dt<4;dt++) oac[dt] = (f32x16)0.f;
    float m = -1e30f, l = 0.f;

    auto STAGE = [&](int kvt){
        const char* kg = (const char*)(kt_base + (size_t)kvt*KVBLK*D_);
        #pragma unroll
        for(int i=0;i<4;i++){
            int p = (i*256 + tid)*16;
            int src = p ^ (((p>>8)&7)<<4);
            gl_lds16(kg + src, &kls[p]);
        }
        const char* vg = (const char*)vt_base + (size_t)kvt*KVBLK*2;
        #pragma unroll
        for(int i=0;i<4;i++){
            int p = (i*256 + tid)*16;
            int d = p>>7;
            int src = (p&127) ^ ((d&7)<<4);
            gl_lds16(vg + (size_t)d*(S_*2) + src, &vls[p]);
        }
    };

    const int nkv    = 2*c + 2;
    const int kvmaxw = 2*c + (wave >> 1);        // waves 0,1 skip the last tile

    for(int kvt=0; kvt<nkv; ++kvt){
        if (kvt) __syncthreads();                // everyone done reading buf
        STAGE(kvt);
        __syncthreads();                         // stage complete (vmcnt drain)

        if (kvt <= kvmaxw){
            const int kv0 = kvt*64;
            // ---- S^T = K . Q^T : lane col q=qg, 32 kv rows across regs+hi ----
            f32x16 sa0=(f32x16)0.f, sa1=(f32x16)0.f;
            const int sz = (ln&7)<<4;
            __builtin_amdgcn_s_setprio(1);
            #pragma unroll
            for(int kk=0;kk<8;kk++){
                int cb = kk*32 + hi*16;
                short8 k0 = *(const short8*)&kls[(ln*256 + cb) ^ sz];
                short8 k1 = *(const short8*)&kls[((ln+32)*256 + cb) ^ sz];
                sa0 = MFMA32(k0, qf[kk], sa0);
                sa1 = MFMA32(k1, qf[kk], sa1);
            }
            __builtin_amdgcn_s_setprio(0);
            // ---- causal mask (diagonal band only) ----
            if (kv0 + 63 > q0 + wave*32){
                #pragma unroll
                for(int r=0;r<16;r++){
                    int kvl = (r&3) + 8*(r>>2) + 4*hi;
                    if (kv0 + kvl      > qg) sa0[r] = -1e30f;
                    if (kv0 + 32 + kvl > qg) sa1[r] = -1e30f;
                }
            }
            // ---- online softmax with defer-max (THR=8, log2 domain) ----
            float pm = sa0[0];
            #pragma unroll
            for(int r=1;r<16;r++) pm = fmaxf(pm, sa0[r]);
            #pragma unroll
            for(int r=0;r<16;r++) pm = fmaxf(pm, sa1[r]);
            pm = fmaxf(pm, __shfl_xor(pm, 32));
            if (!__all(pm <= m + 8.f)){
                float mn = fmaxf(m, pm);
                float sf = __builtin_amdgcn_exp2f(m - mn);
                m = mn; l *= sf;
                #pragma unroll
                for(int dt=0;dt<4;dt++){
                    #pragma unroll
                    for(int r=0;r<16;r++) oac[dt][r] *= sf;
                }
            }
            float ps = 0.f;
            #pragma unroll
            for(int r=0;r<16;r++){ sa0[r] = __builtin_amdgcn_exp2f(sa0[r]-m); ps += sa0[r]; }
            #pragma unroll
            for(int r=0;r<16;r++){ sa1[r] = __builtin_amdgcn_exp2f(sa1[r]-m); ps += sa1[r]; }
            l += ps + __shfl_xor(ps, 32);
            // ---- P -> bf16 PV fragments ----
            short8 pa0 = pfrag(hi, sa0[0],sa0[1],sa0[2], sa0[3], sa0[4], sa0[5], sa0[6], sa0[7]);
            short8 pa1 = pfrag(hi, sa0[8],sa0[9],sa0[10],sa0[11],sa0[12],sa0[13],sa0[14],sa0[15]);
            short8 pa2 = pfrag(hi, sa1[0],sa1[1],sa1[2], sa1[3], sa1[4], sa1[5], sa1[6], sa1[7]);
            short8 pa3 = pfrag(hi, sa1[8],sa1[9],sa1[10],sa1[11],sa1[12],sa1[13],sa1[14],sa1[15]);
            // ---- O^T += V^T . P^T : lane col q=qg, d rows across regs+hi ----
            __builtin_amdgcn_s_setprio(1);
            #pragma unroll
            for(int dt=0;dt<4;dt++){
                int rb = (dt*32 + ln)*128;
                short8 v0 = *(const short8*)&vls[(rb +   0 + hi*16) ^ sz];
                oac[dt] = MFMA32(v0, pa0, oac[dt]);
                short8 v1 = *(const short8*)&vls[(rb +  32 + hi*16) ^ sz];
                oac[dt] = MFMA32(v1, pa1, oac[dt]);
                short8 v2 = *(const short8*)&vls[(rb +  64 + hi*16) ^ sz];
                oac[dt] = MFMA32(v2, pa2, oac[dt]);
                short8 v3 = *(const short8*)&vls[(rb +  96 + hi*16) ^ sz];
                oac[dt] = MFMA32(v3, pa3, oac[dt]);
            }
            __builtin_amdgcn_s_setprio(0);
        }
    }

    // ---- epilogue: O[qg][d] = O^T regs / l ; d = 32dt + 8rr + 4hi + j ----
    float rinv = 1.0f / l;
    float* op = out + ((size_t)(b*S_ + qg)*H_ + h)*D_;
    #pragma unroll
    for(int dt=0;dt<4;dt++){
        #pragma unroll
        for(int rr=0;rr<4;rr++){
            f32x4 o4;
            o4[0]=oac[dt][rr*4+0]*rinv;
            o4[1]=oac[dt][rr*4+1]*rinv;
            o4[2]=oac[dt][rr*4+2]*rinv;
            o4[3]=oac[dt][rr*4+3]*rinv;
            *(f32x4*)(op + dt*32 + rr*8 + hi*4) = o4;
        }
    }
}

extern "C" void kernel_launch(void* const* d_in, const int* in_sizes, int n_in,
                              void* d_out, int out_size, void* d_ws, size_t ws_size,
                              hipStream_t stream) {
    const float* q = (const float*)d_in[0];
    const float* k = (const float*)d_in[1];
    const float* v = (const float*)d_in[2];
    float* out = (float*)d_out;

    short* kb = (short*)d_ws;                                  // 8 MB
    short* vt = (short*)((char*)d_ws + (size_t)2*HK_*S_*D_*2); // next 8 MB

    prep<<<dim3(4096+1024), dim3(256), 0, stream>>>(k, v, kb, vt);
    attn_fwd<<<dim3(1024), dim3(256), 0, stream>>>(q, kb, vt, out);
}

// Round 7
// 135.784 us; speedup vs baseline: 3.4293x; 3.4293x over previous
//
#include <hip/hip_runtime.h>
#include <hip/hip_bf16.h>

typedef __attribute__((ext_vector_type(8))) short short8;
typedef __attribute__((ext_vector_type(4))) short short4v;
typedef __attribute__((ext_vector_type(4))) float f32x4;
typedef __attribute__((ext_vector_type(16))) float f32x16;

#define MFMA32(a,b,c) __builtin_amdgcn_mfma_f32_32x32x16_bf16(a,b,c,0,0,0)

static __device__ __forceinline__ short f2bf(float f){
    union{float f;unsigned u;}x; x.f=f;
    unsigned r=(x.u+0x7FFFu+((x.u>>16)&1u))>>16;
    return (short)r;
}

static __device__ __forceinline__ unsigned pkbf(float lo, float hi){
    unsigned r;
    asm("v_cvt_pk_bf16_f32 %0, %1, %2" : "=v"(r) : "v"(lo), "v"(hi));
    return r;
}

static __device__ __forceinline__ void gl_lds16(const void* g, void* l){
    __builtin_amdgcn_global_load_lds(
        (const __attribute__((address_space(1))) unsigned int*)g,
        (__attribute__((address_space(3))) unsigned int*)l, 16, 0, 0);
}

// build PV B-fragment: lane (ln,hi) needs P[q=ln][kv = chunk + hi*8 + e], e=0..7.
// own regs hold kv (r&3)+8*(r>>2)+4*hi; partner (lane^32) holds the other half.
static __device__ __forceinline__ short8 pfrag(int hi,
        float e0,float e1,float e2,float e3,
        float e4,float e5,float e6,float e7){
    unsigned a01 = pkbf(e0,e1), a23 = pkbf(e2,e3);
    unsigned a45 = pkbf(e4,e5), a67 = pkbf(e6,e7);
    unsigned b01 = __shfl_xor(a01, 32);
    unsigned b23 = __shfl_xor(a23, 32);
    unsigned b45 = __shfl_xor(a45, 32);
    unsigned b67 = __shfl_xor(a67, 32);
    union{ unsigned u[4]; short8 s; } w;
    w.u[0] = hi ? b45 : a01;
    w.u[1] = hi ? b67 : a23;
    w.u[2] = hi ? a45 : b01;
    w.u[3] = hi ? a67 : b23;
    return w.s;
}

// B=2, S=2048, H=32, HK=8, D=128, G=4
constexpr int S_=2048, H_=32, HK_=8, D_=128;
constexpr int KVBLK=64;

// ---- fused prepass: K repack -> bf16 [B,HK,S,D]; V transpose -> bf16 [B,HK,D,S] ----
__global__ __launch_bounds__(256) void prep(const float* __restrict__ k, const float* __restrict__ v,
                                            short* __restrict__ kb, short* __restrict__ vt){
    __shared__ short tile[64*65];
    int bid = blockIdx.x;
    if (bid < 4096){
        int t = bid*256 + threadIdx.x;
        int e = t*4;
        int d  = e & 127;
        int hk = (e>>7) & 7;
        int s  = (e>>10) & 2047;
        int b  = e>>21;
        f32x4 x = *(const f32x4*)(k + ((size_t)((b*S_+s)*HK_+hk))*D_ + d);
        short4v o;
        o[0]=f2bf(x[0]); o[1]=f2bf(x[1]); o[2]=f2bf(x[2]); o[3]=f2bf(x[3]);
        *(short4v*)(kb + ((size_t)((b*HK_+hk)*S_+s))*D_ + d) = o;
    } else {
        bid -= 4096;
        int d0 = (bid & 1)*64;
        int s0 = ((bid>>1) & 31)*64;
        int hk = (bid>>6) & 7;
        int b  = bid>>9;
        int tid = threadIdx.x;
        #pragma unroll
        for(int i=0;i<4;i++){
            int idx = i*1024 + tid*4;
            int r = idx>>6, c = idx&63;
            f32x4 x = *(const f32x4*)(v + ((size_t)((b*S_+s0+r)*HK_+hk))*D_ + d0 + c);
            tile[(c+0)*65 + r] = f2bf(x[0]);
            tile[(c+1)*65 + r] = f2bf(x[1]);
            tile[(c+2)*65 + r] = f2bf(x[2]);
            tile[(c+3)*65 + r] = f2bf(x[3]);
        }
        __syncthreads();
        #pragma unroll
        for(int i=0;i<4;i++){
            int idx = i*1024 + tid*4;
            int dr = idx>>6, c = idx&63;
            short4v o;
            o[0]=tile[dr*65+c]; o[1]=tile[dr*65+c+1]; o[2]=tile[dr*65+c+2]; o[3]=tile[dr*65+c+3];
            *(short4v*)(vt + ((size_t)((b*HK_+hk)*D_ + d0+dr))*S_ + s0 + c) = o;
        }
    }
}

// ---- main attention: block = 4 waves; waves 0,1 on heavy 64-row sub-chunk,
// waves 2,3 on light sub-chunk; every block = 66 wave-tiles (uniform). ----
__global__ __launch_bounds__(256,2) void attn_fwd(
    const float* __restrict__ q, const short* __restrict__ kb,
    const short* __restrict__ vtb, float* __restrict__ out)
{
    // K tile [64][128]bf16 (rows 256B), V^T tile [128][64]bf16 (rows 128B),
    // single-buffered, XOR-swizzled (^((row&7)<<4))  -> 32 KB total
    __shared__ __align__(16) unsigned char kls[KVBLK*D_*2];   // 16KB
    __shared__ __align__(16) unsigned char vls[D_*KVBLK*2];   // 16KB

    const int bid  = blockIdx.x;                 // 1024 blocks
    const int xcd  = bid & 7;                    // 2 (b,hk) KV groups per XCD L2
    const int rest = bid >> 3;                   // 0..127
    const int kvg  = xcd*2 + (rest & 1);         // 0..15 = b*8+hk
    const int b    = kvg >> 3;
    const int hk   = kvg & 7;
    const int rest2= rest >> 1;                  // 0..63
    const int h    = hk*4 + (rest2 & 3);
    const int p    = rest2 >> 2;                 // 0..15: light sub-chunk id

    const int tid  = threadIdx.x;
    const int wave = tid >> 6;                   // 0..3
    const int ln   = tid & 31;
    const int hi   = (tid >> 5) & 1;
    const int qsub = (wave < 2) ? (31 - p) : p;  // this wave's 64-row sub-chunk
    const int qg   = qsub*64 + (wave&1)*32 + ln; // this lane's q row/column

    const float qscale = 0.08838834764831845f * 1.4426950408889634f; // /sqrt(D)*log2e

    const short* kt_base = kb  + (size_t)(b*HK_+hk)*S_*D_;
    const short* vt_base = vtb + (size_t)(b*HK_+hk)*D_*S_;

    // ---- Q fragments: lane holds Q[qg][16kk+8hi .. +7], scaled ----
    short8 qf[8];
    {
        const float* qp = q + ((size_t)(b*S_ + qg)*H_ + h)*D_;
        #pragma unroll
        for(int kk=0;kk<8;kk++){
            int d0 = kk*16 + hi*8;
            f32x4 a = *(const f32x4*)(qp + d0);
            f32x4 cc= *(const f32x4*)(qp + d0 + 4);
            union{ unsigned u[4]; short8 s; } w;
            w.u[0]=pkbf(a[0]*qscale, a[1]*qscale);
            w.u[1]=pkbf(a[2]*qscale, a[3]*qscale);
            w.u[2]=pkbf(cc[0]*qscale, cc[1]*qscale);
            w.u[3]=pkbf(cc[2]*qscale, cc[3]*qscale);
            qf[kk]=w.s;
        }
    }

    f32x16 oac[4];
    #pragma unroll
    for(int dt=0;dt<4;dt++) oac[dt] = (f32x16)0.f;
    float m = -1e30f, l = 0.f;

    auto STAGE = [&](int kvt){
        const char* kg = (const char*)(kt_base + (size_t)kvt*KVBLK*D_);
        #pragma unroll
        for(int i=0;i<4;i++){
            int pp = (i*256 + tid)*16;
            int src = pp ^ (((pp>>8)&7)<<4);
            gl_lds16(kg + src, &kls[pp]);
        }
        const char* vg = (const char*)vt_base + (size_t)kvt*KVBLK*2;
        #pragma unroll
        for(int i=0;i<4;i++){
            int pp = (i*256 + tid)*16;
            int d = pp>>7;
            int src = (pp&127) ^ ((d&7)<<4);
            gl_lds16(vg + (size_t)d*(S_*2) + src, &vls[pp]);
        }
    };

    const int nkv    = 32 - p;                   // heavy sub-chunk's extent
    const int kvmaxw = qsub;                     // last tile this wave needs

    for(int kvt=0; kvt<nkv; ++kvt){
        if (kvt) __syncthreads();                // everyone done reading buf
        STAGE(kvt);
        __syncthreads();                         // stage complete (vmcnt drain)

        if (kvt <= kvmaxw){
            const int kv0 = kvt*64;
            // ---- S^T = K . Q^T : lane col q=qg, 32 kv rows across regs+hi ----
            f32x16 sa0=(f32x16)0.f, sa1=(f32x16)0.f;
            const int sz = (ln&7)<<4;
            __builtin_amdgcn_s_setprio(1);
            #pragma unroll
            for(int kk=0;kk<8;kk++){
                int cb = kk*32 + hi*16;
                short8 k0 = *(const short8*)&kls[(ln*256 + cb) ^ sz];
                short8 k1 = *(const short8*)&kls[((ln+32)*256 + cb) ^ sz];
                sa0 = MFMA32(k0, qf[kk], sa0);
                sa1 = MFMA32(k1, qf[kk], sa1);
            }
            __builtin_amdgcn_s_setprio(0);
            // ---- causal mask (diagonal tile only) ----
            if (kv0 + 63 > qsub*64 + (wave&1)*32){
                #pragma unroll
                for(int r=0;r<16;r++){
                    int kvl = (r&3) + 8*(r>>2) + 4*hi;
                    if (kv0 + kvl      > qg) sa0[r] = -1e30f;
                    if (kv0 + 32 + kvl > qg) sa1[r] = -1e30f;
                }
            }
            // ---- online softmax with defer-max (THR=8, log2 domain) ----
            float pm = sa0[0];
            #pragma unroll
            for(int r=1;r<16;r++) pm = fmaxf(pm, sa0[r]);
            #pragma unroll
            for(int r=0;r<16;r++) pm = fmaxf(pm, sa1[r]);
            pm = fmaxf(pm, __shfl_xor(pm, 32));
            if (!__all(pm <= m + 8.f)){
                float mn = fmaxf(m, pm);
                float sf = __builtin_amdgcn_exp2f(m - mn);
                m = mn; l *= sf;
                #pragma unroll
                for(int dt=0;dt<4;dt++){
                    #pragma unroll
                    for(int r=0;r<16;r++) oac[dt][r] *= sf;
                }
            }
            float ps = 0.f;
            #pragma unroll
            for(int r=0;r<16;r++){ sa0[r] = __builtin_amdgcn_exp2f(sa0[r]-m); ps += sa0[r]; }
            #pragma unroll
            for(int r=0;r<16;r++){ sa1[r] = __builtin_amdgcn_exp2f(sa1[r]-m); ps += sa1[r]; }
            l += ps + __shfl_xor(ps, 32);
            // ---- P -> bf16 PV fragments ----
            short8 pa0 = pfrag(hi, sa0[0],sa0[1],sa0[2], sa0[3], sa0[4], sa0[5], sa0[6], sa0[7]);
            short8 pa1 = pfrag(hi, sa0[8],sa0[9],sa0[10],sa0[11],sa0[12],sa0[13],sa0[14],sa0[15]);
            short8 pa2 = pfrag(hi, sa1[0],sa1[1],sa1[2], sa1[3], sa1[4], sa1[5], sa1[6], sa1[7]);
            short8 pa3 = pfrag(hi, sa1[8],sa1[9],sa1[10],sa1[11],sa1[12],sa1[13],sa1[14],sa1[15]);
            // ---- O^T += V^T . P^T : lane col q=qg, d rows across regs+hi ----
            __builtin_amdgcn_s_setprio(1);
            #pragma unroll
            for(int dt=0;dt<4;dt++){
                int rb = (dt*32 + ln)*128;
                short8 v0 = *(const short8*)&vls[(rb +   0 + hi*16) ^ sz];
                oac[dt] = MFMA32(v0, pa0, oac[dt]);
                short8 v1 = *(const short8*)&vls[(rb +  32 + hi*16) ^ sz];
                oac[dt] = MFMA32(v1, pa1, oac[dt]);
                short8 v2 = *(const short8*)&vls[(rb +  64 + hi*16) ^ sz];
                oac[dt] = MFMA32(v2, pa2, oac[dt]);
                short8 v3 = *(const short8*)&vls[(rb +  96 + hi*16) ^ sz];
                oac[dt] = MFMA32(v3, pa3, oac[dt]);
            }
            __builtin_amdgcn_s_setprio(0);
        }
    }

    // ---- epilogue: O[qg][d] = O^T regs / l ; d = 32dt + 8rr + 4hi + j ----
    float rinv = 1.0f / l;
    float* op = out + ((size_t)(b*S_ + qg)*H_ + h)*D_;
    #pragma unroll
    for(int dt=0;dt<4;dt++){
        #pragma unroll
        for(int rr=0;rr<4;rr++){
            f32x4 o4;
            o4[0]=oac[dt][rr*4+0]*rinv;
            o4[1]=oac[dt][rr*4+1]*rinv;
            o4[2]=oac[dt][rr*4+2]*rinv;
            o4[3]=oac[dt][rr*4+3]*rinv;
            *(f32x4*)(op + dt*32 + rr*8 + hi*4) = o4;
        }
    }
}

extern "C" void kernel_launch(void* const* d_in, const int* in_sizes, int n_in,
                              void* d_out, int out_size, void* d_ws, size_t ws_size,
                              hipStream_t stream) {
    const float* q = (const float*)d_in[0];
    const float* k = (const float*)d_in[1];
    const float* v = (const float*)d_in[2];
    float* out = (float*)d_out;

    short* kb = (short*)d_ws;                                  // 8 MB
    short* vt = (short*)((char*)d_ws + (size_t)2*HK_*S_*D_*2); // next 8 MB

    prep<<<dim3(4096+1024), dim3(256), 0, stream>>>(k, v, kb, vt);
    attn_fwd<<<dim3(1024), dim3(256), 0, stream>>>(q, kb, vt, out);
}

// Round 8
// 116.625 us; speedup vs baseline: 3.9927x; 1.1643x over previous
//
#include <hip/hip_runtime.h>
#include <hip/hip_bf16.h>

typedef __attribute__((ext_vector_type(8))) short short8;
typedef __attribute__((ext_vector_type(4))) short short4v;
typedef __attribute__((ext_vector_type(4))) float f32x4;
typedef __attribute__((ext_vector_type(16))) float f32x16;

#define MFMA32(a,b,c) __builtin_amdgcn_mfma_f32_32x32x16_bf16(a,b,c,0,0,0)

static __device__ __forceinline__ short f2bf(float f){
    union{float f;unsigned u;}x; x.f=f;
    unsigned r=(x.u+0x7FFFu+((x.u>>16)&1u))>>16;
    return (short)r;
}

static __device__ __forceinline__ unsigned pkbf(float lo, float hi){
    unsigned r;
    asm("v_cvt_pk_bf16_f32 %0, %1, %2" : "=v"(r) : "v"(lo), "v"(hi));
    return r;
}

static __device__ __forceinline__ void gl_lds16(const void* g, void* l){
    __builtin_amdgcn_global_load_lds(
        (const __attribute__((address_space(1))) unsigned int*)g,
        (__attribute__((address_space(3))) unsigned int*)l, 16, 0, 0);
}

// build PV B-fragment: lane (ln,hi) needs P[q=ln][kv = chunk + hi*8 + e], e=0..7.
// own regs hold kv (r&3)+8*(r>>2)+4*hi; partner (lane^32) holds the other half.
static __device__ __forceinline__ short8 pfrag(int hi,
        float e0,float e1,float e2,float e3,
        float e4,float e5,float e6,float e7){
    unsigned a01 = pkbf(e0,e1), a23 = pkbf(e2,e3);
    unsigned a45 = pkbf(e4,e5), a67 = pkbf(e6,e7);
    unsigned b01 = __shfl_xor(a01, 32);
    unsigned b23 = __shfl_xor(a23, 32);
    unsigned b45 = __shfl_xor(a45, 32);
    unsigned b67 = __shfl_xor(a67, 32);
    union{ unsigned u[4]; short8 s; } w;
    w.u[0] = hi ? b45 : a01;
    w.u[1] = hi ? b67 : a23;
    w.u[2] = hi ? a45 : b01;
    w.u[3] = hi ? a67 : b23;
    return w.s;
}

// B=2, S=2048, H=32, HK=8, D=128, G=4
constexpr int S_=2048, H_=32, HK_=8, D_=128;
constexpr int KVBLK=64;

// ---- fused prepass: K repack -> bf16 [B,HK,S,D]; V transpose -> bf16 [B,HK,D,S] ----
__global__ __launch_bounds__(256) void prep(const float* __restrict__ k, const float* __restrict__ v,
                                            short* __restrict__ kb, short* __restrict__ vt){
    __shared__ short tile[64*65];
    int bid = blockIdx.x;
    if (bid < 4096){
        int t = bid*256 + threadIdx.x;
        int e = t*4;
        int d  = e & 127;
        int hk = (e>>7) & 7;
        int s  = (e>>10) & 2047;
        int b  = e>>21;
        f32x4 x = *(const f32x4*)(k + ((size_t)((b*S_+s)*HK_+hk))*D_ + d);
        short4v o;
        o[0]=f2bf(x[0]); o[1]=f2bf(x[1]); o[2]=f2bf(x[2]); o[3]=f2bf(x[3]);
        *(short4v*)(kb + ((size_t)((b*HK_+hk)*S_+s))*D_ + d) = o;
    } else {
        bid -= 4096;
        int d0 = (bid & 1)*64;
        int s0 = ((bid>>1) & 31)*64;
        int hk = (bid>>6) & 7;
        int b  = bid>>9;
        int tid = threadIdx.x;
        #pragma unroll
        for(int i=0;i<4;i++){
            int idx = i*1024 + tid*4;
            int r = idx>>6, c = idx&63;
            f32x4 x = *(const f32x4*)(v + ((size_t)((b*S_+s0+r)*HK_+hk))*D_ + d0 + c);
            tile[(c+0)*65 + r] = f2bf(x[0]);
            tile[(c+1)*65 + r] = f2bf(x[1]);
            tile[(c+2)*65 + r] = f2bf(x[2]);
            tile[(c+3)*65 + r] = f2bf(x[3]);
        }
        __syncthreads();
        #pragma unroll
        for(int i=0;i<4;i++){
            int idx = i*1024 + tid*4;
            int dr = idx>>6, c = idx&63;
            short4v o;
            o[0]=tile[dr*65+c]; o[1]=tile[dr*65+c+1]; o[2]=tile[dr*65+c+2]; o[3]=tile[dr*65+c+3];
            *(short4v*)(vt + ((size_t)((b*HK_+hk)*D_ + d0+dr))*S_ + s0 + c) = o;
        }
    }
}

// ---- main attention: 4 waves x 32 q-rows, paired q-chunks (15-p, p),
//      counted-vmcnt pipeline (stage never drains to 0 in main loop) ----
__global__ __launch_bounds__(256,2) void attn_fwd(
    const float* __restrict__ q, const short* __restrict__ kb,
    const short* __restrict__ vtb, float* __restrict__ out)
{
    // K tile [64][128]bf16 (rows 256B), V^T tile [128][64]bf16 (rows 128B),
    // double-buffered, XOR-swizzled (^((row&7)<<4))
    __shared__ __align__(16) unsigned char kls[2][KVBLK*D_*2];   // 2x16KB
    __shared__ __align__(16) unsigned char vls[2][D_*KVBLK*2];   // 2x16KB

    const int bid  = blockIdx.x;                 // 512 blocks
    // XCD-aware: consecutive work per XCD shares (b,hk) KV in its L2
    const int wg   = (bid & 7)*64 + (bid >> 3);  // bijective, 512 % 8 == 0
    const int kvg  = wg >> 5;                    // 0..15 = b*8+hk
    const int b    = kvg >> 3;
    const int hk   = kvg & 7;
    const int rr_  = wg & 31;
    const int h    = hk*4 + (rr_ >> 3);
    const int pair = rr_ & 7;                    // q-chunk pair (pair, 15-pair)

    const int tid  = threadIdx.x;
    const int wave = tid >> 6;                   // 0..3
    const int ln   = tid & 31;
    const int hi   = (tid >> 5) & 1;

    const float qscale = 0.08838834764831845f * 1.4426950408889634f; // /sqrt(D)*log2e

    const short* kt_base = kb  + (size_t)(b*HK_+hk)*S_*D_;
    const short* vt_base = vtb + (size_t)(b*HK_+hk)*D_*S_;

    auto STAGE = [&](int bufi, int kvt){
        const char* kg = (const char*)(kt_base + (size_t)kvt*KVBLK*D_);
        #pragma unroll
        for(int i=0;i<4;i++){
            int p = (i*256 + tid)*16;
            int src = p ^ (((p>>8)&7)<<4);
            gl_lds16(kg + src, &kls[bufi][p]);
        }
        const char* vg = (const char*)vt_base + (size_t)kvt*KVBLK*2;
        #pragma unroll
        for(int i=0;i<4;i++){
            int p = (i*256 + tid)*16;
            int d = p>>7;
            int src = (p&127) ^ ((d&7)<<4);
            gl_lds16(vg + (size_t)d*(S_*2) + src, &vls[bufi][p]);
        }
    };

    int cur = 0;
    STAGE(0, 0);       // 8 loads in flight; landing enforced by vmcnt(8)+barrier in iter 0

    for(int phase=0; phase<2; ++phase){
        const int c      = phase ? pair : 15-pair;   // heavy chunk first
        const int nkv    = 2*c + 2;
        const int kvmaxw = 2*c + (wave >> 1);        // waves 0,1 skip last tile
        const int qg     = c*128 + wave*32 + ln;

        // ---- Q fragments for this chunk ----
        short8 qf[8];
        {
            const float* qp = q + ((size_t)(b*S_ + qg)*H_ + h)*D_;
            #pragma unroll
            for(int kk=0;kk<8;kk++){
                int d0 = kk*16 + hi*8;
                f32x4 a = *(const f32x4*)(qp + d0);
                f32x4 cc= *(const f32x4*)(qp + d0 + 4);
                union{ unsigned u[4]; short8 s; } w;
                w.u[0]=pkbf(a[0]*qscale, a[1]*qscale);
                w.u[1]=pkbf(a[2]*qscale, a[3]*qscale);
                w.u[2]=pkbf(cc[0]*qscale, cc[1]*qscale);
                w.u[3]=pkbf(cc[2]*qscale, cc[3]*qscale);
                qf[kk]=w.s;
            }
        }

        f32x16 oac[4];
        #pragma unroll
        for(int dt=0;dt<4;dt++) oac[dt] = (f32x16)0.f;
        float m = -1e30f, l = 0.f;

        for(int kvt=0; kvt<nkv; ++kvt){
            int nxt = (kvt+1 < nkv) ? (kvt+1) : (phase==0 ? 0 : -1);
            if (nxt >= 0){
                STAGE(cur^1, nxt);                       // 8 new loads in flight
                asm volatile("s_waitcnt vmcnt(8)" ::: "memory");  // stage(kvt) landed (mine)
            } else {
                asm volatile("s_waitcnt vmcnt(0)" ::: "memory");  // final tile: drain
            }
            __builtin_amdgcn_s_barrier();                // all waves' stage(kvt) landed
            __builtin_amdgcn_sched_barrier(0);

            if (kvt <= kvmaxw){
                const int kv0 = kvt*64;
                // ---- S^T = K . Q^T : lane col q=qg, 32 kv rows across regs+hi ----
                f32x16 sa0=(f32x16)0.f, sa1=(f32x16)0.f;
                const int sz = (ln&7)<<4;
                __builtin_amdgcn_s_setprio(1);
                #pragma unroll
                for(int kk=0;kk<8;kk++){
                    int cb = kk*32 + hi*16;
                    short8 k0 = *(const short8*)&kls[cur][(ln*256 + cb) ^ sz];
                    short8 k1 = *(const short8*)&kls[cur][((ln+32)*256 + cb) ^ sz];
                    sa0 = MFMA32(k0, qf[kk], sa0);
                    sa1 = MFMA32(k1, qf[kk], sa1);
                }
                __builtin_amdgcn_s_setprio(0);
                // ---- causal mask (diagonal band only) ----
                if (kv0 + 63 > c*128 + wave*32){
                    #pragma unroll
                    for(int r=0;r<16;r++){
                        int kvl = (r&3) + 8*(r>>2) + 4*hi;
                        if (kv0 + kvl      > qg) sa0[r] = -1e30f;
                        if (kv0 + 32 + kvl > qg) sa1[r] = -1e30f;
                    }
                }
                // ---- online softmax with defer-max (THR=8, log2 domain) ----
                float pm = sa0[0];
                #pragma unroll
                for(int r=1;r<16;r++) pm = fmaxf(pm, sa0[r]);
                #pragma unroll
                for(int r=0;r<16;r++) pm = fmaxf(pm, sa1[r]);
                pm = fmaxf(pm, __shfl_xor(pm, 32));
                if (!__all(pm <= m + 8.f)){
                    float mn = fmaxf(m, pm);
                    float sf = __builtin_amdgcn_exp2f(m - mn);
                    m = mn; l *= sf;
                    #pragma unroll
                    for(int dt=0;dt<4;dt++){
                        #pragma unroll
                        for(int r=0;r<16;r++) oac[dt][r] *= sf;
                    }
                }
                float ps = 0.f;
                #pragma unroll
                for(int r=0;r<16;r++){ sa0[r] = __builtin_amdgcn_exp2f(sa0[r]-m); ps += sa0[r]; }
                #pragma unroll
                for(int r=0;r<16;r++){ sa1[r] = __builtin_amdgcn_exp2f(sa1[r]-m); ps += sa1[r]; }
                l += ps + __shfl_xor(ps, 32);
                // ---- P -> bf16 PV fragments ----
                short8 pa0 = pfrag(hi, sa0[0],sa0[1],sa0[2], sa0[3], sa0[4], sa0[5], sa0[6], sa0[7]);
                short8 pa1 = pfrag(hi, sa0[8],sa0[9],sa0[10],sa0[11],sa0[12],sa0[13],sa0[14],sa0[15]);
                short8 pa2 = pfrag(hi, sa1[0],sa1[1],sa1[2], sa1[3], sa1[4], sa1[5], sa1[6], sa1[7]);
                short8 pa3 = pfrag(hi, sa1[8],sa1[9],sa1[10],sa1[11],sa1[12],sa1[13],sa1[14],sa1[15]);
                // ---- O^T += V^T . P^T : lane col q=qg, d rows across regs+hi ----
                __builtin_amdgcn_s_setprio(1);
                #pragma unroll
                for(int dt=0;dt<4;dt++){
                    int rb = (dt*32 + ln)*128;
                    short8 v0 = *(const short8*)&vls[cur][(rb +   0 + hi*16) ^ sz];
                    oac[dt] = MFMA32(v0, pa0, oac[dt]);
                    short8 v1 = *(const short8*)&vls[cur][(rb +  32 + hi*16) ^ sz];
                    oac[dt] = MFMA32(v1, pa1, oac[dt]);
                    short8 v2 = *(const short8*)&vls[cur][(rb +  64 + hi*16) ^ sz];
                    oac[dt] = MFMA32(v2, pa2, oac[dt]);
                    short8 v3 = *(const short8*)&vls[cur][(rb +  96 + hi*16) ^ sz];
                    oac[dt] = MFMA32(v3, pa3, oac[dt]);
                }
                __builtin_amdgcn_s_setprio(0);
            }
            __builtin_amdgcn_sched_barrier(0);
            __builtin_amdgcn_s_barrier();                // all done reading buf[cur]
            cur ^= 1;
        }

        // ---- epilogue for this chunk: O[qg][d] = O^T regs / l ----
        float rinv = 1.0f / l;
        float* op = out + ((size_t)(b*S_ + qg)*H_ + h)*D_;
        #pragma unroll
        for(int dt=0;dt<4;dt++){
            #pragma unroll
            for(int rr=0;rr<4;rr++){
                f32x4 o4;
                o4[0]=oac[dt][rr*4+0]*rinv;
                o4[1]=oac[dt][rr*4+1]*rinv;
                o4[2]=oac[dt][rr*4+2]*rinv;
                o4[3]=oac[dt][rr*4+3]*rinv;
                *(f32x4*)(op + dt*32 + rr*8 + hi*4) = o4;
            }
        }
    }
}

extern "C" void kernel_launch(void* const* d_in, const int* in_sizes, int n_in,
                              void* d_out, int out_size, void* d_ws, size_t ws_size,
                              hipStream_t stream) {
    const float* q = (const float*)d_in[0];
    const float* k = (const float*)d_in[1];
    const float* v = (const float*)d_in[2];
    float* out = (float*)d_out;

    short* kb = (short*)d_ws;                                  // 8 MB
    short* vt = (short*)((char*)d_ws + (size_t)2*HK_*S_*D_*2); // next 8 MB

    prep<<<dim3(4096+1024), dim3(256), 0, stream>>>(k, v, kb, vt);
    attn_fwd<<<dim3(512), dim3(256), 0, stream>>>(q, kb, vt, out);
}